// Round 4
// baseline (1188.202 us; speedup 1.0000x reference)
//
#include <hip/hip_runtime.h>
#include <hip/hip_bf16.h>

#define NE 1600000
#define NN 100000

typedef __attribute__((ext_vector_type(8))) short s16x8;
typedef __attribute__((ext_vector_type(4))) float f32x4;
typedef __attribute__((ext_vector_type(4))) int i32x4;
typedef __attribute__((ext_vector_type(4))) uint u32x4;

__device__ __forceinline__ ushort f2b(float v) {
  union { __hip_bfloat16 h; ushort u; } c; c.h = __float2bfloat16(v); return c.u;
}
// HW packed f32x2 -> bf16x2 (RNE). lo = a, hi = b — matches (b<<16)|a packing.
__device__ __forceinline__ uint cvtpk(float a, float b) {
  uint r;
  asm("v_cvt_pk_bf16_f32 %0, %1, %2" : "=v"(r) : "v"(a), "v"(b));
  return r;
}
__device__ __forceinline__ uint pkrelu(float a, float b) {
  a = fmaxf(a, 0.f); b = fmaxf(b, 0.f);
  return cvtpk(a, b);
}

// ---- prep: weights -> MFMA fragment order (bf16).
// Fragment for chunk (kb,nb): lane l holds W[kb*32 + (l>>4)*8 + j][nb*16 + (l&15)], j=0..7.
// Stored frag-major: elem index = ((kb*NF+nb)*64 + lane)*8 + j.
// For CONSUMER weights (W1,W2,W3 of each net) the K index is permuted so that the
// producer's packed MFMA output registers are directly the next layer's B-fragment.
__global__ void prep_weights(const float* s0, const float* s1, const float* s2, const float* s3,
                             const float* s4, const float* s5, const float* s6, const float* s7,
                             ushort* dst) {
  const int Ks[8]   = {10, 128, 128, 128, 7, 128, 128, 128};
  const int Ns[8]   = {128, 128, 128, 2, 128, 128, 128, 2};
  const int NFs[8]  = {8, 8, 8, 1, 8, 8, 8, 1};
  const int KCs[8]  = {1, 4, 4, 4, 1, 4, 4, 4};
  const int offs[8] = {0, 4096, 20480, 36864, 38912, 43008, 59392, 75776};
  const float* srcs[8] = {s0, s1, s2, s3, s4, s5, s6, s7};
  int b = blockIdx.x;
  int K = Ks[b], N = Ns[b], NF = NFs[b];
  int cnt = KCs[b] * NF * 512;
  const float* src = srcs[b];
  bool isConsumer = (b != 0 && b != 4);
  ushort* d = dst + offs[b];
  for (int idx = threadIdx.x; idx < cnt; idx += blockDim.x) {
    int f = idx >> 9, r = idx & 511, lane = r >> 3, j = r & 7;
    int kb = f / NF, nb = f - kb * NF;
    int k = kb * 32 + ((lane >> 4) << 3) + j;      // fragment k-slot
    int n = (nb << 4) + (lane & 15);
    int ks = isConsumer ? ((k & 96) | ((k & 4) << 2) | ((k & 24) >> 1) | (k & 3)) : k;
    float v = (ks < K && n < N) ? src[ks * N + n] : 0.f;
    d[idx] = f2b(v);
  }
}

// ---- main: swapped-operand dataflow, H kept entirely in registers between layers.
// Per wave: 64 edges/nodes per batch. acc[ht][et] (C/D frags) -> relu+cvt_pk -> ph[4][4]
// (u32x4) which IS the next layer's B-fragment thanks to the consumer K-permutation.
// 16 waves/block (4/SIMD), no barriers in the main loop.
template <int MODE>
__global__ __launch_bounds__(1024, 4)
void gnn_kernel(const float* __restrict__ nodes,
                const int* __restrict__ eidx,
                float* __restrict__ pooled,
                const ushort* __restrict__ wsrc,
                const float* __restrict__ b0g, const float* __restrict__ b1g,
                const float* __restrict__ b2g, const float* __restrict__ b3g,
                float* __restrict__ out) {
  extern __shared__ char smem[];
  ushort* wlds = (ushort*)smem;             // 77824 B
  float* bias0 = (float*)(smem + 77824);    // 128
  float* bias1 = bias0 + 128;               // 128
  float* bias2 = bias1 + 128;               // 128
  float* bias3 = bias2 + 128;               // 16 (2 valid)
  char* stage = smem + 79424;               // 16 waves * 4096 (xbuf only)

  {
    i32x4* dw = (i32x4*)wlds;
    const i32x4* sw = (const i32x4*)wsrc;
    for (int i = threadIdx.x; i < 4864; i += 1024) dw[i] = sw[i];
    if (threadIdx.x < 128) {
      int i = threadIdx.x;
      bias0[i] = b0g[i]; bias1[i] = b1g[i]; bias2[i] = b2g[i];
    }
    if (threadIdx.x < 16) bias3[threadIdx.x] = (threadIdx.x < 2) ? b3g[threadIdx.x] : 0.f;
  }

  const int wv = threadIdx.x >> 6;
  const int l = threadIdx.x & 63;
  const int q = l >> 4;
  const int m16 = l & 15;
  char* xbuf = stage + wv * 4096;  // [64 rows][32 k] bf16, 64B rows, 16B slot ^ (row&3)

  {
    u32x4 z = {0, 0, 0, 0};
#pragma unroll
    for (int i = 0; i < 4; i++) *(u32x4*)(xbuf + l * 64 + i * 16) = z;
  }
  __syncthreads();

  const ushort* W0p = wlds;
  const ushort* W1p = wlds + 4096;
  const ushort* W2p = wlds + 20480;
  const ushort* W3p = wlds + 36864;

  int wid = blockIdx.x * 16 + wv;
  int nwv = gridDim.x * 16;
  const int NB = (MODE == 0) ? (NE / 64) : ((NN + 63) / 64);

  // gather prefetch registers
  float g0 = 0, g1 = 0, g2 = 0, g3 = 0, g4 = 0, g5 = 0, g6 = 0, g7 = 0, g8 = 0, g9 = 0;
  if (wid < NB) {
    if (MODE == 0) {
      int ge = (wid << 6) + l;
      int s = eidx[ge], r = eidx[NE + ge];
      g0 = nodes[s * 5 + 0]; g1 = nodes[s * 5 + 1]; g2 = nodes[s * 5 + 2];
      g3 = nodes[s * 5 + 3]; g4 = nodes[s * 5 + 4];
      g5 = nodes[r * 5 + 0]; g6 = nodes[r * 5 + 1]; g7 = nodes[r * 5 + 2];
      g8 = nodes[r * 5 + 3]; g9 = nodes[r * 5 + 4];
    } else {
      int e = (wid << 6) + l;
      if (e < NN) {
        g0 = nodes[e * 5 + 0]; g1 = nodes[e * 5 + 1]; g2 = nodes[e * 5 + 2];
        g3 = nodes[e * 5 + 3]; g4 = nodes[e * 5 + 4];
        float2 pl = *(const float2*)&pooled[e * 2];
        g5 = pl.x; g6 = pl.y;
      }
    }
  }

#pragma unroll 1
  for (int b = wid; b < NB; b += nwv) {
    const int rbase = b << 6;
    // receiver indices for the head scatter (MODE 0)
    int rc0 = 0, rc1 = 0, rc2 = 0, rc3 = 0;
    if (MODE == 0 && q == 0) {
      rc0 = eidx[NE + rbase + m16];
      rc1 = eidx[NE + rbase + 16 + m16];
      rc2 = eidx[NE + rbase + 32 + m16];
      rc3 = eidx[NE + rbase + 48 + m16];
    }
    // consume prefetched gather -> xbuf (row l), packed b32 writes, swizzled
    {
      constexpr int npr = (MODE == 0) ? 5 : 4;
      uint pr[5];
      if (MODE == 0) {
        pr[0] = cvtpk(g0, g1); pr[1] = cvtpk(g2, g3); pr[2] = cvtpk(g4, g5);
        pr[3] = cvtpk(g6, g7); pr[4] = cvtpk(g8, g9);
      } else {
        pr[0] = cvtpk(g0, g1); pr[1] = cvtpk(g2, g3); pr[2] = cvtpk(g4, g5);
        pr[3] = cvtpk(g6, 0.f);
      }
#pragma unroll
      for (int p = 0; p < npr; p++)
        *(uint*)(xbuf + l * 64 + (((p >> 2) ^ (l & 3)) << 4) + ((p & 3) << 2)) = pr[p];
    }
    // prefetch next batch
    {
      int b2 = b + nwv;
      if (b2 < NB) {
        if (MODE == 0) {
          int ge = (b2 << 6) + l;
          int s = eidx[ge], r = eidx[NE + ge];
          g0 = nodes[s * 5 + 0]; g1 = nodes[s * 5 + 1]; g2 = nodes[s * 5 + 2];
          g3 = nodes[s * 5 + 3]; g4 = nodes[s * 5 + 4];
          g5 = nodes[r * 5 + 0]; g6 = nodes[r * 5 + 1]; g7 = nodes[r * 5 + 2];
          g8 = nodes[r * 5 + 3]; g9 = nodes[r * 5 + 4];
        } else {
          int e = (b2 << 6) + l;
          if (e < NN) {
            g0 = nodes[e * 5 + 0]; g1 = nodes[e * 5 + 1]; g2 = nodes[e * 5 + 2];
            g3 = nodes[e * 5 + 3]; g4 = nodes[e * 5 + 4];
            float2 pl = *(const float2*)&pooled[e * 2];
            g5 = pl.x; g6 = pl.y;
          } else { g0 = g1 = g2 = g3 = g4 = g5 = g6 = 0.f; }
        }
      }
    }

    f32x4 acc[8][4];
    u32x4 ph[4][4];

    // ---- layer 0: K=32 (10/7 valid rows), bias0 via C-operand ----
    {
      s16x8 xf[4];
#pragma unroll
      for (int et = 0; et < 4; et++) {
        int e = (et << 4) + m16;
        xf[et] = *(const s16x8*)(xbuf + e * 64 + ((q ^ (e & 3)) << 4));
      }
#pragma unroll
      for (int ht = 0; ht < 8; ht++) {
        s16x8 wf = *(const s16x8*)(W0p + (((ht << 6) + l) << 3));
        f32x4 b0f = *(const f32x4*)(bias0 + (ht << 4) + (q << 2));
#pragma unroll
        for (int et = 0; et < 4; et++)
          acc[ht][et] = __builtin_amdgcn_mfma_f32_16x16x32_bf16(wf, xf[et], b0f, 0, 0, 0);
      }
#pragma unroll
      for (int ht = 0; ht < 8; ht++)
#pragma unroll
        for (int et = 0; et < 4; et++) {
          f32x4 v = acc[ht][et];
          ph[ht >> 1][et][2 * (ht & 1)]     = pkrelu(v[0], v[1]);
          ph[ht >> 1][et][2 * (ht & 1) + 1] = pkrelu(v[2], v[3]);
        }
    }
    // ---- layers 1 & 2: K=128, bias via C-operand at kb=0, H in registers ----
#pragma unroll
    for (int L = 0; L < 2; L++) {
      const ushort* W = L ? W2p : W1p;
      const float* bias = L ? bias2 : bias1;
#pragma unroll
      for (int kb = 0; kb < 4; kb++) {
#pragma unroll
        for (int ht = 0; ht < 8; ht++) {
          s16x8 wf = *(const s16x8*)(W + ((((kb << 3) + ht) << 6) + l) * 8);
          if (kb == 0) {
            f32x4 bf = *(const f32x4*)(bias + (ht << 4) + (q << 2));
#pragma unroll
            for (int et = 0; et < 4; et++)
              acc[ht][et] = __builtin_amdgcn_mfma_f32_16x16x32_bf16(
                  wf, __builtin_bit_cast(s16x8, ph[kb][et]), bf, 0, 0, 0);
          } else {
#pragma unroll
            for (int et = 0; et < 4; et++)
              acc[ht][et] = __builtin_amdgcn_mfma_f32_16x16x32_bf16(
                  wf, __builtin_bit_cast(s16x8, ph[kb][et]), acc[ht][et], 0, 0, 0);
          }
        }
      }
#pragma unroll
      for (int ht = 0; ht < 8; ht++)
#pragma unroll
        for (int et = 0; et < 4; et++) {
          f32x4 v = acc[ht][et];
          ph[ht >> 1][et][2 * (ht & 1)]     = pkrelu(v[0], v[1]);
          ph[ht >> 1][et][2 * (ht & 1) + 1] = pkrelu(v[2], v[3]);
        }
    }
    // ---- head: K=128, N=2 (rows 0,1 -> q==0 lanes), bias3 via C-operand ----
    {
      f32x4 ah[4];
      f32x4 b3f = *(const f32x4*)(bias3 + (q << 2));
#pragma unroll
      for (int kb = 0; kb < 4; kb++) {
        s16x8 wf = *(const s16x8*)(W3p + (((kb << 6) + l) << 3));
        if (kb == 0) {
#pragma unroll
          for (int et = 0; et < 4; et++)
            ah[et] = __builtin_amdgcn_mfma_f32_16x16x32_bf16(
                wf, __builtin_bit_cast(s16x8, ph[kb][et]), b3f, 0, 0, 0);
        } else {
#pragma unroll
          for (int et = 0; et < 4; et++)
            ah[et] = __builtin_amdgcn_mfma_f32_16x16x32_bf16(
                wf, __builtin_bit_cast(s16x8, ph[kb][et]), ah[et], 0, 0, 0);
        }
      }
      if (q == 0) {
#pragma unroll
        for (int et = 0; et < 4; et++) {
          int e = rbase + (et << 4) + m16;
          float mv0 = ah[et][0], mv1 = ah[et][1];
          if (MODE == 0) {
            int rc = (et == 0) ? rc0 : (et == 1) ? rc1 : (et == 2) ? rc2 : rc3;
            unsafeAtomicAdd(&pooled[rc * 2], mv0);
            unsafeAtomicAdd(&pooled[rc * 2 + 1], mv1);
          } else if (e < NN) {
            out[e * 5 + 2] = nodes[e * 5 + 2] + mv0;
            out[e * 5 + 3] = nodes[e * 5 + 3] + mv1;
          }
        }
      } else if (MODE == 1 && q == 1) {
#pragma unroll
        for (int et = 0; et < 4; et++) {
          int e = rbase + (et << 4) + m16;
          if (e < NN) { out[e * 5] = nodes[e * 5]; out[e * 5 + 1] = nodes[e * 5 + 1]; }
        }
      } else if (MODE == 1 && q == 2) {
#pragma unroll
        for (int et = 0; et < 4; et++) {
          int e = rbase + (et << 4) + m16;
          if (e < NN) out[e * 5 + 4] = nodes[e * 5 + 4];
        }
      }
    }
  }
}

extern "C" void kernel_launch(void* const* d_in, const int* in_sizes, int n_in,
                              void* d_out, int out_size, void* d_ws, size_t ws_size,
                              hipStream_t stream) {
  const float* nodes = (const float*)d_in[0];
  const int* eidx = (const int*)d_in[1];
  const float* Wm0 = (const float*)d_in[2];  const float* bm0 = (const float*)d_in[3];
  const float* Wm1 = (const float*)d_in[4];  const float* bm1 = (const float*)d_in[5];
  const float* Wm2 = (const float*)d_in[6];  const float* bm2 = (const float*)d_in[7];
  const float* Wm3 = (const float*)d_in[8];  const float* bm3 = (const float*)d_in[9];
  const float* Wu0 = (const float*)d_in[10]; const float* bu0 = (const float*)d_in[11];
  const float* Wu1 = (const float*)d_in[12]; const float* bu1 = (const float*)d_in[13];
  const float* Wu2 = (const float*)d_in[14]; const float* bu2 = (const float*)d_in[15];
  const float* Wu3 = (const float*)d_in[16]; const float* bu3 = (const float*)d_in[17];

  float* pooled = (float*)d_ws;                     // NN*2 f32 = 800000 B
  ushort* wbuf = (ushort*)((char*)d_ws + 800000);   // 2*38912 prearranged bf16

  hipMemsetAsync(pooled, 0, NN * 2 * sizeof(float), stream);
  prep_weights<<<8, 256, 0, stream>>>(Wm0, Wm1, Wm2, Wm3, Wu0, Wu1, Wu2, Wu3, wbuf);

  size_t lds = 144960;  // 77824 wts + 1600 bias + 16*4096 xbuf
  gnn_kernel<0><<<256, 1024, lds, stream>>>(nodes, eidx, pooled, wbuf,
                                            bm0, bm1, bm2, bm3, nullptr);
  gnn_kernel<1><<<256, 1024, lds, stream>>>(nodes, nullptr, pooled, wbuf + 38912,
                                            bu0, bu1, bu2, bu3, (float*)d_out);
}

// Round 5
// 259.075 us; speedup vs baseline: 4.5863x; 4.5863x over previous
//
#include <hip/hip_runtime.h>
#include <hip/hip_bf16.h>

#define NE 1600000
#define NN 100000

typedef __attribute__((ext_vector_type(8))) short s16x8;
typedef __attribute__((ext_vector_type(4))) float f32x4;
typedef __attribute__((ext_vector_type(4))) int i32x4;
typedef __attribute__((ext_vector_type(4))) uint u32x4;

__device__ __forceinline__ ushort f2b(float v) {
  union { __hip_bfloat16 h; ushort u; } c; c.h = __float2bfloat16(v); return c.u;
}
// HW packed f32x2 -> bf16x2 (RNE). lo = a, hi = b — matches (b<<16)|a packing.
// Verified on-device in round 4 (absmax identical to software path).
__device__ __forceinline__ uint cvtpk(float a, float b) {
  uint r;
  asm("v_cvt_pk_bf16_f32 %0, %1, %2" : "=v"(r) : "v"(a), "v"(b));
  return r;
}
__device__ __forceinline__ uint pkrelu(float a, float b) {
  a = fmaxf(a, 0.f); b = fmaxf(b, 0.f);
  return cvtpk(a, b);
}

// ---- prep: weights -> MFMA fragment order (bf16).
// Fragment for chunk (kb,nb): lane l holds W[kb*32 + (l>>4)*8 + j][nb*16 + (l&15)], j=0..7.
// Stored frag-major: elem index = ((kb*NF+nb)*64 + lane)*8 + j.
// For CONSUMER weights (W1,W2,W3 of each net) the K index is permuted so that the
// producer's packed MFMA output registers are directly the next layer's B-fragment.
__global__ void prep_weights(const float* s0, const float* s1, const float* s2, const float* s3,
                             const float* s4, const float* s5, const float* s6, const float* s7,
                             ushort* dst) {
  const int Ks[8]   = {10, 128, 128, 128, 7, 128, 128, 128};
  const int Ns[8]   = {128, 128, 128, 2, 128, 128, 128, 2};
  const int NFs[8]  = {8, 8, 8, 1, 8, 8, 8, 1};
  const int KCs[8]  = {1, 4, 4, 4, 1, 4, 4, 4};
  const int offs[8] = {0, 4096, 20480, 36864, 38912, 43008, 59392, 75776};
  const float* srcs[8] = {s0, s1, s2, s3, s4, s5, s6, s7};
  int b = blockIdx.x;
  int K = Ks[b], N = Ns[b], NF = NFs[b];
  int cnt = KCs[b] * NF * 512;
  const float* src = srcs[b];
  bool isConsumer = (b != 0 && b != 4);
  ushort* d = dst + offs[b];
  for (int idx = threadIdx.x; idx < cnt; idx += blockDim.x) {
    int f = idx >> 9, r = idx & 511, lane = r >> 3, j = r & 7;
    int kb = f / NF, nb = f - kb * NF;
    int k = kb * 32 + ((lane >> 4) << 3) + j;      // fragment k-slot
    int n = (nb << 4) + (lane & 15);
    int ks = isConsumer ? ((k & 96) | ((k & 4) << 2) | ((k & 24) >> 1) | (k & 3)) : k;
    float v = (ks < K && n < N) ? src[ks * N + n] : 0.f;
    d[idx] = f2b(v);
  }
}

// ---- main: swapped-operand dataflow, H kept entirely in registers between layers.
// Per wave: 64 edges/nodes per batch. acc[ht][et] (C/D frags) -> relu+cvt_pk -> ph[4][4]
// (u32x4) which IS the next layer's B-fragment thanks to the consumer K-permutation.
// Geometry identical to round 3 (512 thr, VGPR=128, no spill); only cvtpk differs.
template <int MODE>
__global__ __launch_bounds__(512, 2)
void gnn_kernel(const float* __restrict__ nodes,
                const int* __restrict__ eidx,
                float* __restrict__ pooled,
                const ushort* __restrict__ wsrc,
                const float* __restrict__ b0g, const float* __restrict__ b1g,
                const float* __restrict__ b2g, const float* __restrict__ b3g,
                float* __restrict__ out) {
  extern __shared__ char smem[];
  ushort* wlds = (ushort*)smem;             // 77824 B
  float* bias0 = (float*)(smem + 77824);    // 128
  float* bias1 = bias0 + 128;               // 128
  float* bias2 = bias1 + 128;               // 128
  float* bias3 = bias2 + 128;               // 16 (2 valid)
  char* stage = smem + 79424;               // 8 waves * 4096 (xbuf only)

  {
    i32x4* dw = (i32x4*)wlds;
    const i32x4* sw = (const i32x4*)wsrc;
    for (int i = threadIdx.x; i < 4864; i += 512) dw[i] = sw[i];
    for (int i = threadIdx.x; i < 128; i += 512) {
      bias0[i] = b0g[i]; bias1[i] = b1g[i]; bias2[i] = b2g[i];
    }
    if (threadIdx.x < 16) bias3[threadIdx.x] = (threadIdx.x < 2) ? b3g[threadIdx.x] : 0.f;
  }

  const int wv = threadIdx.x >> 6;
  const int l = threadIdx.x & 63;
  const int q = l >> 4;
  const int m16 = l & 15;
  char* xbuf = stage + wv * 4096;  // [64 rows][32 k] bf16, 64B rows, 16B slot ^ (row&3)

  {
    u32x4 z = {0, 0, 0, 0};
#pragma unroll
    for (int i = 0; i < 4; i++) *(u32x4*)(xbuf + l * 64 + i * 16) = z;
  }
  __syncthreads();

  const ushort* W0p = wlds;
  const ushort* W1p = wlds + 4096;
  const ushort* W2p = wlds + 20480;
  const ushort* W3p = wlds + 36864;

  int wid = blockIdx.x * 8 + wv;
  int nwv = gridDim.x * 8;
  const int NB = (MODE == 0) ? (NE / 64) : ((NN + 63) / 64);

  // gather prefetch registers
  float g0 = 0, g1 = 0, g2 = 0, g3 = 0, g4 = 0, g5 = 0, g6 = 0, g7 = 0, g8 = 0, g9 = 0;
  if (wid < NB) {
    if (MODE == 0) {
      int ge = (wid << 6) + l;
      int s = eidx[ge], r = eidx[NE + ge];
      g0 = nodes[s * 5 + 0]; g1 = nodes[s * 5 + 1]; g2 = nodes[s * 5 + 2];
      g3 = nodes[s * 5 + 3]; g4 = nodes[s * 5 + 4];
      g5 = nodes[r * 5 + 0]; g6 = nodes[r * 5 + 1]; g7 = nodes[r * 5 + 2];
      g8 = nodes[r * 5 + 3]; g9 = nodes[r * 5 + 4];
    } else {
      int e = (wid << 6) + l;
      if (e < NN) {
        g0 = nodes[e * 5 + 0]; g1 = nodes[e * 5 + 1]; g2 = nodes[e * 5 + 2];
        g3 = nodes[e * 5 + 3]; g4 = nodes[e * 5 + 4];
        float2 pl = *(const float2*)&pooled[e * 2];
        g5 = pl.x; g6 = pl.y;
      }
    }
  }

#pragma unroll 1
  for (int b = wid; b < NB; b += nwv) {
    const int rbase = b << 6;
    // receiver indices for the head scatter (MODE 0)
    int rc0 = 0, rc1 = 0, rc2 = 0, rc3 = 0;
    if (MODE == 0 && q == 0) {
      rc0 = eidx[NE + rbase + m16];
      rc1 = eidx[NE + rbase + 16 + m16];
      rc2 = eidx[NE + rbase + 32 + m16];
      rc3 = eidx[NE + rbase + 48 + m16];
    }
    // consume prefetched gather -> xbuf (row l), packed b32 writes, swizzled
    {
      constexpr int npr = (MODE == 0) ? 5 : 4;
      uint pr[5];
      if (MODE == 0) {
        pr[0] = cvtpk(g0, g1); pr[1] = cvtpk(g2, g3); pr[2] = cvtpk(g4, g5);
        pr[3] = cvtpk(g6, g7); pr[4] = cvtpk(g8, g9);
      } else {
        pr[0] = cvtpk(g0, g1); pr[1] = cvtpk(g2, g3); pr[2] = cvtpk(g4, g5);
        pr[3] = cvtpk(g6, 0.f);
      }
#pragma unroll
      for (int p = 0; p < npr; p++)
        *(uint*)(xbuf + l * 64 + (((p >> 2) ^ (l & 3)) << 4) + ((p & 3) << 2)) = pr[p];
    }
    // prefetch next batch
    {
      int b2 = b + nwv;
      if (b2 < NB) {
        if (MODE == 0) {
          int ge = (b2 << 6) + l;
          int s = eidx[ge], r = eidx[NE + ge];
          g0 = nodes[s * 5 + 0]; g1 = nodes[s * 5 + 1]; g2 = nodes[s * 5 + 2];
          g3 = nodes[s * 5 + 3]; g4 = nodes[s * 5 + 4];
          g5 = nodes[r * 5 + 0]; g6 = nodes[r * 5 + 1]; g7 = nodes[r * 5 + 2];
          g8 = nodes[r * 5 + 3]; g9 = nodes[r * 5 + 4];
        } else {
          int e = (b2 << 6) + l;
          if (e < NN) {
            g0 = nodes[e * 5 + 0]; g1 = nodes[e * 5 + 1]; g2 = nodes[e * 5 + 2];
            g3 = nodes[e * 5 + 3]; g4 = nodes[e * 5 + 4];
            float2 pl = *(const float2*)&pooled[e * 2];
            g5 = pl.x; g6 = pl.y;
          } else { g0 = g1 = g2 = g3 = g4 = g5 = g6 = 0.f; }
        }
      }
    }

    f32x4 acc[8][4];
    u32x4 ph[4][4];

    // ---- layer 0: K=32 (10/7 valid rows), bias0 via C-operand ----
    {
      s16x8 xf[4];
#pragma unroll
      for (int et = 0; et < 4; et++) {
        int e = (et << 4) + m16;
        xf[et] = *(const s16x8*)(xbuf + e * 64 + ((q ^ (e & 3)) << 4));
      }
#pragma unroll
      for (int ht = 0; ht < 8; ht++) {
        s16x8 wf = *(const s16x8*)(W0p + (((ht << 6) + l) << 3));
        f32x4 b0f = *(const f32x4*)(bias0 + (ht << 4) + (q << 2));
#pragma unroll
        for (int et = 0; et < 4; et++)
          acc[ht][et] = __builtin_amdgcn_mfma_f32_16x16x32_bf16(wf, xf[et], b0f, 0, 0, 0);
      }
#pragma unroll
      for (int ht = 0; ht < 8; ht++)
#pragma unroll
        for (int et = 0; et < 4; et++) {
          f32x4 v = acc[ht][et];
          ph[ht >> 1][et][2 * (ht & 1)]     = pkrelu(v[0], v[1]);
          ph[ht >> 1][et][2 * (ht & 1) + 1] = pkrelu(v[2], v[3]);
        }
    }
    // ---- layers 1 & 2: K=128, bias via C-operand at kb=0, H in registers ----
#pragma unroll
    for (int L = 0; L < 2; L++) {
      const ushort* W = L ? W2p : W1p;
      const float* bias = L ? bias2 : bias1;
#pragma unroll
      for (int kb = 0; kb < 4; kb++) {
#pragma unroll
        for (int ht = 0; ht < 8; ht++) {
          s16x8 wf = *(const s16x8*)(W + ((((kb << 3) + ht) << 6) + l) * 8);
          if (kb == 0) {
            f32x4 bf = *(const f32x4*)(bias + (ht << 4) + (q << 2));
#pragma unroll
            for (int et = 0; et < 4; et++)
              acc[ht][et] = __builtin_amdgcn_mfma_f32_16x16x32_bf16(
                  wf, __builtin_bit_cast(s16x8, ph[kb][et]), bf, 0, 0, 0);
          } else {
#pragma unroll
            for (int et = 0; et < 4; et++)
              acc[ht][et] = __builtin_amdgcn_mfma_f32_16x16x32_bf16(
                  wf, __builtin_bit_cast(s16x8, ph[kb][et]), acc[ht][et], 0, 0, 0);
          }
        }
      }
#pragma unroll
      for (int ht = 0; ht < 8; ht++)
#pragma unroll
        for (int et = 0; et < 4; et++) {
          f32x4 v = acc[ht][et];
          ph[ht >> 1][et][2 * (ht & 1)]     = pkrelu(v[0], v[1]);
          ph[ht >> 1][et][2 * (ht & 1) + 1] = pkrelu(v[2], v[3]);
        }
    }
    // ---- head: K=128, N=2 (rows 0,1 -> q==0 lanes), bias3 via C-operand ----
    {
      f32x4 ah[4];
      f32x4 b3f = *(const f32x4*)(bias3 + (q << 2));
#pragma unroll
      for (int kb = 0; kb < 4; kb++) {
        s16x8 wf = *(const s16x8*)(W3p + (((kb << 6) + l) << 3));
        if (kb == 0) {
#pragma unroll
          for (int et = 0; et < 4; et++)
            ah[et] = __builtin_amdgcn_mfma_f32_16x16x32_bf16(
                wf, __builtin_bit_cast(s16x8, ph[kb][et]), b3f, 0, 0, 0);
        } else {
#pragma unroll
          for (int et = 0; et < 4; et++)
            ah[et] = __builtin_amdgcn_mfma_f32_16x16x32_bf16(
                wf, __builtin_bit_cast(s16x8, ph[kb][et]), ah[et], 0, 0, 0);
        }
      }
      if (q == 0) {
#pragma unroll
        for (int et = 0; et < 4; et++) {
          int e = rbase + (et << 4) + m16;
          float mv0 = ah[et][0], mv1 = ah[et][1];
          if (MODE == 0) {
            int rc = (et == 0) ? rc0 : (et == 1) ? rc1 : (et == 2) ? rc2 : rc3;
            unsafeAtomicAdd(&pooled[rc * 2], mv0);
            unsafeAtomicAdd(&pooled[rc * 2 + 1], mv1);
          } else if (e < NN) {
            out[e * 5 + 2] = nodes[e * 5 + 2] + mv0;
            out[e * 5 + 3] = nodes[e * 5 + 3] + mv1;
          }
        }
      } else if (MODE == 1 && q == 1) {
#pragma unroll
        for (int et = 0; et < 4; et++) {
          int e = rbase + (et << 4) + m16;
          if (e < NN) { out[e * 5] = nodes[e * 5]; out[e * 5 + 1] = nodes[e * 5 + 1]; }
        }
      } else if (MODE == 1 && q == 2) {
#pragma unroll
        for (int et = 0; et < 4; et++) {
          int e = rbase + (et << 4) + m16;
          if (e < NN) out[e * 5 + 4] = nodes[e * 5 + 4];
        }
      }
    }
  }
}

extern "C" void kernel_launch(void* const* d_in, const int* in_sizes, int n_in,
                              void* d_out, int out_size, void* d_ws, size_t ws_size,
                              hipStream_t stream) {
  const float* nodes = (const float*)d_in[0];
  const int* eidx = (const int*)d_in[1];
  const float* Wm0 = (const float*)d_in[2];  const float* bm0 = (const float*)d_in[3];
  const float* Wm1 = (const float*)d_in[4];  const float* bm1 = (const float*)d_in[5];
  const float* Wm2 = (const float*)d_in[6];  const float* bm2 = (const float*)d_in[7];
  const float* Wm3 = (const float*)d_in[8];  const float* bm3 = (const float*)d_in[9];
  const float* Wu0 = (const float*)d_in[10]; const float* bu0 = (const float*)d_in[11];
  const float* Wu1 = (const float*)d_in[12]; const float* bu1 = (const float*)d_in[13];
  const float* Wu2 = (const float*)d_in[14]; const float* bu2 = (const float*)d_in[15];
  const float* Wu3 = (const float*)d_in[16]; const float* bu3 = (const float*)d_in[17];

  float* pooled = (float*)d_ws;                     // NN*2 f32 = 800000 B
  ushort* wbuf = (ushort*)((char*)d_ws + 800000);   // 2*38912 prearranged bf16

  hipMemsetAsync(pooled, 0, NN * 2 * sizeof(float), stream);
  prep_weights<<<8, 256, 0, stream>>>(Wm0, Wm1, Wm2, Wm3, Wu0, Wu1, Wu2, Wu3, wbuf);

  size_t lds = 112192;  // 77824 wts + 1600 bias + 8*4096 xbuf
  gnn_kernel<0><<<256, 512, lds, stream>>>(nodes, eidx, pooled, wbuf,
                                           bm0, bm1, bm2, bm3, nullptr);
  gnn_kernel<1><<<256, 512, lds, stream>>>(nodes, nullptr, pooled, wbuf + 38912,
                                           bu0, bu1, bu2, bu3, (float*)d_out);
}

// Round 6
// 233.581 us; speedup vs baseline: 5.0869x; 1.1091x over previous
//
#include <hip/hip_runtime.h>
#include <hip/hip_bf16.h>

#define NE 1600000
#define NN 100000

typedef __attribute__((ext_vector_type(8))) short s16x8;
typedef __attribute__((ext_vector_type(4))) float f32x4;
typedef __attribute__((ext_vector_type(4))) int i32x4;
typedef __attribute__((ext_vector_type(4))) uint u32x4;

__device__ __forceinline__ ushort f2b(float v) {
  union { __hip_bfloat16 h; ushort u; } c; c.h = __float2bfloat16(v); return c.u;
}
// HW packed f32x2 -> bf16x2 (RNE). lo = a, hi = b. Verified on-device (r4/r5).
__device__ __forceinline__ uint cvtpk(float a, float b) {
  uint r;
  asm("v_cvt_pk_bf16_f32 %0, %1, %2" : "=v"(r) : "v"(a), "v"(b));
  return r;
}
__device__ __forceinline__ uint pkrelu(float a, float b) {
  a = fmaxf(a, 0.f); b = fmaxf(b, 0.f);
  return cvtpk(a, b);
}

// ---- prep: weights -> MFMA fragment order (bf16).
// Fragment (kb,nb): lane l holds W[kb*32 + (l>>4)*8 + j][nb*16 + (l&15)], j=0..7.
// Stored frag-major: elem index = ((kb*NF+nb)*64 + lane)*8 + j.
// PRODUCER (layer-0) K layout matches the xbuf write pattern:
//   edge net (b=0):  k0-4 = sender rows 0-4, k8-12 = receiver rows 5-9, k13 = bias
//   node net (b=4):  k0-4 = node rows 0-4,   k8-9  = pooled rows 5-6,   k10 = bias
// CONSUMER weights (W1,W2,W3): K permuted so producer's packed MFMA output regs
// are directly the next layer's B-fragment (verified r3/r5).
__global__ void prep_weights(const float* s0, const float* s1, const float* s2, const float* s3,
                             const float* s4, const float* s5, const float* s6, const float* s7,
                             const float* bm0, const float* bu0, ushort* dst) {
  const int Ks[8]   = {10, 128, 128, 128, 7, 128, 128, 128};
  const int Ns[8]   = {128, 128, 128, 2, 128, 128, 128, 2};
  const int NFs[8]  = {8, 8, 8, 1, 8, 8, 8, 1};
  const int KCs[8]  = {1, 4, 4, 4, 1, 4, 4, 4};
  const int offs[8] = {0, 4096, 20480, 36864, 38912, 43008, 59392, 75776};
  const float* srcs[8] = {s0, s1, s2, s3, s4, s5, s6, s7};
  int b = blockIdx.x;
  int K = Ks[b], N = Ns[b], NF = NFs[b];
  int cnt = KCs[b] * NF * 512;
  const float* src = srcs[b];
  bool isProducer = (b == 0 || b == 4);
  int F1 = (b == 0) ? 5 : 2;            // receiver/pooled span length
  int kbias = (b == 0) ? 13 : 10;
  const float* bp = (b == 0) ? bm0 : bu0;
  ushort* d = dst + offs[b];
  for (int idx = threadIdx.x; idx < cnt; idx += blockDim.x) {
    int f = idx >> 9, r = idx & 511, lane = r >> 3, j = r & 7;
    int kb = f / NF, nb = f - kb * NF;
    int k = kb * 32 + ((lane >> 4) << 3) + j;      // fragment k-slot
    int n = (nb << 4) + (lane & 15);
    float v = 0.f;
    if (n < N) {
      if (isProducer) {
        int row = -1;
        if (k < 5) row = k;
        else if (k >= 8 && k < 8 + F1) row = k - 3;
        if (row >= 0 && row < K) v = src[row * N + n];
        else if (k == kbias) v = bp[n];
      } else {
        int ks = (k & 96) | ((k & 4) << 2) | ((k & 24) >> 1) | (k & 3);
        if (ks < K) v = src[ks * N + n];
      }
    }
    d[idx] = f2b(v);
  }
}

// ---- main: swapped-operand dataflow, H in registers between layers.
// Per wave: 32 edges/nodes per batch (et=2) -> ~150 regs -> 3 waves/SIMD.
// 768 threads = 12 waves/block, 1 block/CU, no barriers in the main loop.
template <int MODE>
__global__ __launch_bounds__(768, 3)
void gnn_kernel(const float* __restrict__ nodes,
                const int* __restrict__ eidx,
                float* __restrict__ pooled,
                const ushort* __restrict__ wsrc,
                const float* __restrict__ b1g, const float* __restrict__ b2g,
                const float* __restrict__ b3g,
                float* __restrict__ out) {
  extern __shared__ char smem[];
  ushort* wlds = (ushort*)smem;             // 77824 B
  float* bias1 = (float*)(smem + 77824);    // 128
  float* bias2 = bias1 + 128;               // 128
  float* bias3 = bias2 + 128;               // 16 (2 valid)
  char* stage = smem + 79424;               // 12 waves * 2048 (xbuf)

  {
    i32x4* dw = (i32x4*)wlds;
    const i32x4* sw = (const i32x4*)wsrc;
    for (int i = threadIdx.x; i < 4864; i += 768) dw[i] = sw[i];
    if (threadIdx.x < 128) {
      int i = threadIdx.x;
      bias1[i] = b1g[i]; bias2[i] = b2g[i];
    }
    if (threadIdx.x < 16) bias3[threadIdx.x] = (threadIdx.x < 2) ? b3g[threadIdx.x] : 0.f;
  }

  const int wv = threadIdx.x >> 6;
  const int l = threadIdx.x & 63;
  const int q = l >> 4;
  const int m16 = l & 15;
  const int h = l >> 5;      // endpoint half (gather) / k-slot16 (xbuf write)
  const int e32 = l & 31;    // edge-in-batch for gather
  char* xbuf = stage + wv * 2048;  // [32 rows][32 k] bf16, 64B rows, slot16 ^ (row&3)

  {
    u32x4 z = {0, 0, 0, 0};
    *(u32x4*)(xbuf + l * 32) = z;
    *(u32x4*)(xbuf + l * 32 + 16) = z;
  }
  __syncthreads();

  const ushort* W0p = wlds;
  const ushort* W1p = wlds + 4096;
  const ushort* W2p = wlds + 20480;
  const ushort* W3p = wlds + 36864;

  // cache W3 fragments (4 x 16B = 16 regs)
  s16x8 w3c[4];
#pragma unroll
  for (int kb = 0; kb < 4; kb++)
    w3c[kb] = *(const s16x8*)(W3p + (((kb << 6) + l) << 3));

  int wid = blockIdx.x * 12 + wv;
  int nwv = gridDim.x * 12;
  const int NB = (MODE == 0) ? (NE / 32) : (NN / 32);  // both divide exactly

  // gather prefetch (2 lanes per edge: h=0 sender/node, h=1 receiver/pooled)
  float g0 = 0, g1 = 0, g2 = 0, g3 = 0, g4 = 0;
  if (wid < NB) {
    if (MODE == 0) {
      int idx = eidx[h * NE + (wid << 5) + e32];
      const float* np_ = nodes + idx * 5;
      g0 = np_[0]; g1 = np_[1]; g2 = np_[2]; g3 = np_[3]; g4 = np_[4];
    } else {
      int e = (wid << 5) + e32;
      if (h == 0) {
        const float* np_ = nodes + e * 5;
        g0 = np_[0]; g1 = np_[1]; g2 = np_[2]; g3 = np_[3]; g4 = np_[4];
      } else {
        float2 pl = *(const float2*)&pooled[e * 2];
        g0 = pl.x; g1 = pl.y;
      }
    }
  }

#pragma unroll 1
  for (int b = wid; b < NB; b += nwv) {
    const int rbase = b << 5;
    // receiver indices for the head scatter (MODE 0)
    int rc0 = 0, rc1 = 0;
    if (MODE == 0 && q == 0) {
      rc0 = eidx[NE + rbase + m16];
      rc1 = eidx[NE + rbase + 16 + m16];
    }
    // consume prefetched gather -> xbuf row e32, slot16 h (swizzled)
    {
      uint pr0, pr1, pr2;
      if (MODE == 0) {
        pr0 = cvtpk(g0, g1); pr1 = cvtpk(g2, g3);
        pr2 = cvtpk(g4, h ? 1.0f : 0.0f);          // bias rides k13 (h=1)
      } else {
        if (h == 0) { pr0 = cvtpk(g0, g1); pr1 = cvtpk(g2, g3); pr2 = cvtpk(g4, 0.f); }
        else        { pr0 = cvtpk(g0, g1); pr1 = cvtpk(1.0f, 0.f); pr2 = 0u; }  // bias k10
      }
      char* wp = xbuf + e32 * 64 + ((h ^ (e32 & 3)) << 4);
      *(uint*)(wp + 0) = pr0;
      *(uint*)(wp + 4) = pr1;
      *(uint*)(wp + 8) = pr2;
    }
    // prefetch next batch
    {
      int b2 = b + nwv;
      if (b2 < NB) {
        if (MODE == 0) {
          int idx = eidx[h * NE + (b2 << 5) + e32];
          const float* np_ = nodes + idx * 5;
          g0 = np_[0]; g1 = np_[1]; g2 = np_[2]; g3 = np_[3]; g4 = np_[4];
        } else {
          int e = (b2 << 5) + e32;
          if (h == 0) {
            const float* np_ = nodes + e * 5;
            g0 = np_[0]; g1 = np_[1]; g2 = np_[2]; g3 = np_[3]; g4 = np_[4];
          } else {
            float2 pl = *(const float2*)&pooled[e * 2];
            g0 = pl.x; g1 = pl.y;
          }
        }
      }
    }

    f32x4 acc[8][2];
    u32x4 ph[4][2];

    // ---- layer 0: K=32 (bias folded into W0), C = 0 ----
    {
      s16x8 xf[2];
#pragma unroll
      for (int et = 0; et < 2; et++) {
        int e = (et << 4) + m16;
        xf[et] = *(const s16x8*)(xbuf + e * 64 + ((q ^ (e & 3)) << 4));
      }
#pragma unroll
      for (int ht = 0; ht < 8; ht++) {
        s16x8 wf = *(const s16x8*)(W0p + (((ht << 6) + l) << 3));
        f32x4 z = {0.f, 0.f, 0.f, 0.f};
        acc[ht][0] = __builtin_amdgcn_mfma_f32_16x16x32_bf16(wf, xf[0], z, 0, 0, 0);
        acc[ht][1] = __builtin_amdgcn_mfma_f32_16x16x32_bf16(wf, xf[1], z, 0, 0, 0);
      }
#pragma unroll
      for (int ht = 0; ht < 8; ht++)
#pragma unroll
        for (int et = 0; et < 2; et++) {
          f32x4 v = acc[ht][et];
          ph[ht >> 1][et][2 * (ht & 1)]     = pkrelu(v[0], v[1]);
          ph[ht >> 1][et][2 * (ht & 1) + 1] = pkrelu(v[2], v[3]);
        }
    }
    // ---- layers 1 & 2: K=128, bias via C-operand at kb=0, H in registers ----
#pragma unroll
    for (int L = 0; L < 2; L++) {
      const ushort* W = L ? W2p : W1p;
      const float* bias = L ? bias2 : bias1;
#pragma unroll
      for (int kb = 0; kb < 4; kb++) {
#pragma unroll
        for (int ht = 0; ht < 8; ht++) {
          s16x8 wf = *(const s16x8*)(W + ((((kb << 3) + ht) << 6) + l) * 8);
          if (kb == 0) {
            f32x4 bf = *(const f32x4*)(bias + (ht << 4) + (q << 2));
            acc[ht][0] = __builtin_amdgcn_mfma_f32_16x16x32_bf16(
                wf, __builtin_bit_cast(s16x8, ph[0][0]), bf, 0, 0, 0);
            acc[ht][1] = __builtin_amdgcn_mfma_f32_16x16x32_bf16(
                wf, __builtin_bit_cast(s16x8, ph[0][1]), bf, 0, 0, 0);
          } else {
            acc[ht][0] = __builtin_amdgcn_mfma_f32_16x16x32_bf16(
                wf, __builtin_bit_cast(s16x8, ph[kb][0]), acc[ht][0], 0, 0, 0);
            acc[ht][1] = __builtin_amdgcn_mfma_f32_16x16x32_bf16(
                wf, __builtin_bit_cast(s16x8, ph[kb][1]), acc[ht][1], 0, 0, 0);
          }
        }
      }
#pragma unroll
      for (int ht = 0; ht < 8; ht++)
#pragma unroll
        for (int et = 0; et < 2; et++) {
          f32x4 v = acc[ht][et];
          ph[ht >> 1][et][2 * (ht & 1)]     = pkrelu(v[0], v[1]);
          ph[ht >> 1][et][2 * (ht & 1) + 1] = pkrelu(v[2], v[3]);
        }
    }
    // ---- head: K=128, N=2 (rows 0,1 -> q==0), W3 from regs, bias3 via C ----
    {
      f32x4 ah[2];
      f32x4 b3f = *(const f32x4*)(bias3 + (q << 2));
#pragma unroll
      for (int kb = 0; kb < 4; kb++) {
        if (kb == 0) {
          ah[0] = __builtin_amdgcn_mfma_f32_16x16x32_bf16(
              w3c[0], __builtin_bit_cast(s16x8, ph[0][0]), b3f, 0, 0, 0);
          ah[1] = __builtin_amdgcn_mfma_f32_16x16x32_bf16(
              w3c[0], __builtin_bit_cast(s16x8, ph[0][1]), b3f, 0, 0, 0);
        } else {
          ah[0] = __builtin_amdgcn_mfma_f32_16x16x32_bf16(
              w3c[kb], __builtin_bit_cast(s16x8, ph[kb][0]), ah[0], 0, 0, 0);
          ah[1] = __builtin_amdgcn_mfma_f32_16x16x32_bf16(
              w3c[kb], __builtin_bit_cast(s16x8, ph[kb][1]), ah[1], 0, 0, 0);
        }
      }
      if (q == 0) {
#pragma unroll
        for (int et = 0; et < 2; et++) {
          int e = rbase + (et << 4) + m16;
          float mv0 = ah[et][0], mv1 = ah[et][1];
          if (MODE == 0) {
            int rc = et ? rc1 : rc0;
            unsafeAtomicAdd(&pooled[rc * 2], mv0);
            unsafeAtomicAdd(&pooled[rc * 2 + 1], mv1);
          } else {
            out[e * 5 + 2] = nodes[e * 5 + 2] + mv0;
            out[e * 5 + 3] = nodes[e * 5 + 3] + mv1;
          }
        }
      } else if (MODE == 1 && q == 1) {
#pragma unroll
        for (int et = 0; et < 2; et++) {
          int e = rbase + (et << 4) + m16;
          out[e * 5] = nodes[e * 5]; out[e * 5 + 1] = nodes[e * 5 + 1];
        }
      } else if (MODE == 1 && q == 2) {
#pragma unroll
        for (int et = 0; et < 2; et++) {
          int e = rbase + (et << 4) + m16;
          out[e * 5 + 4] = nodes[e * 5 + 4];
        }
      }
    }
  }
}

extern "C" void kernel_launch(void* const* d_in, const int* in_sizes, int n_in,
                              void* d_out, int out_size, void* d_ws, size_t ws_size,
                              hipStream_t stream) {
  const float* nodes = (const float*)d_in[0];
  const int* eidx = (const int*)d_in[1];
  const float* Wm0 = (const float*)d_in[2];  const float* bm0 = (const float*)d_in[3];
  const float* Wm1 = (const float*)d_in[4];  const float* bm1 = (const float*)d_in[5];
  const float* Wm2 = (const float*)d_in[6];  const float* bm2 = (const float*)d_in[7];
  const float* Wm3 = (const float*)d_in[8];  const float* bm3 = (const float*)d_in[9];
  const float* Wu0 = (const float*)d_in[10]; const float* bu0 = (const float*)d_in[11];
  const float* Wu1 = (const float*)d_in[12]; const float* bu1 = (const float*)d_in[13];
  const float* Wu2 = (const float*)d_in[14]; const float* bu2 = (const float*)d_in[15];
  const float* Wu3 = (const float*)d_in[16]; const float* bu3 = (const float*)d_in[17];

  float* pooled = (float*)d_ws;                     // NN*2 f32 = 800000 B
  ushort* wbuf = (ushort*)((char*)d_ws + 800000);   // 2*38912 prearranged bf16

  hipMemsetAsync(pooled, 0, NN * 2 * sizeof(float), stream);
  prep_weights<<<8, 256, 0, stream>>>(Wm0, Wm1, Wm2, Wm3, Wu0, Wu1, Wu2, Wu3,
                                      bm0, bu0, wbuf);

  size_t lds = 104000;  // 77824 wts + 1600 bias + 12*2048 xbuf
  gnn_kernel<0><<<256, 768, lds, stream>>>(nodes, eidx, pooled, wbuf,
                                           bm1, bm2, bm3, nullptr);
  gnn_kernel<1><<<256, 768, lds, stream>>>(nodes, nullptr, pooled, wbuf + 38912,
                                           bu1, bu2, bu3, (float*)d_out);
}